// Round 11
// baseline (292.458 us; speedup 1.0000x reference)
//
#include <hip/hip_runtime.h>
#include <hip/hip_fp16.h>

#define DD 300
#define KK 50
#define BB 32
#define SS 8192
#define NN 128
#define LL 64
#define NSEG (BB * NN)   // 4096
#define HH 304           // fp16 row pitch (halfs); 608 B = 16B-aligned rows
#define TMU 8            // segments per k_u block
#define NTU 320
// fallback (r5) constants
#define NW 5
#define NT 320
#define NJ 13
#define NC 5

#define EMB16_BYTES ((size_t)50000 * HH * 2)
#define U_BYTES     ((size_t)NSEG * DD * 4)
#define W16_BYTES   ((size_t)KK * HH * 2)
#define T16_BYTES   ((size_t)64 * HH * 2)

__device__ __forceinline__ float wave_sum(float v) {
    #pragma unroll
    for (int m = 32; m; m >>= 1) v += __shfl_xor(v, m, 64);
    return v;
}
__device__ __forceinline__ float wave_max(float v) {
    #pragma unroll
    for (int m = 32; m; m >>= 1) v = fmaxf(v, __shfl_xor(v, m, 64));
    return v;
}

// ---------- fp16 helpers ----------
__device__ __forceinline__ float dot8(uint4 r, const float u8[8]) {
    const float2 f0 = __half22float2(*(const __half2*)&r.x);
    const float2 f1 = __half22float2(*(const __half2*)&r.y);
    const float2 f2 = __half22float2(*(const __half2*)&r.z);
    const float2 f3 = __half22float2(*(const __half2*)&r.w);
    return f0.x*u8[0] + f0.y*u8[1] + f1.x*u8[2] + f1.y*u8[3]
         + f2.x*u8[4] + f2.y*u8[5] + f3.x*u8[6] + f3.y*u8[7];
}
__device__ __forceinline__ void fma8(float z8[8], float a, uint4 r) {
    const float2 f0 = __half22float2(*(const __half2*)&r.x);
    const float2 f1 = __half22float2(*(const __half2*)&r.y);
    const float2 f2 = __half22float2(*(const __half2*)&r.z);
    const float2 f3 = __half22float2(*(const __half2*)&r.w);
    z8[0] += a*f0.x; z8[1] += a*f0.y; z8[2] += a*f1.x; z8[3] += a*f1.y;
    z8[4] += a*f2.x; z8[5] += a*f2.y; z8[6] += a*f3.x; z8[7] += a*f3.y;
}
// 4 emb16 rows (token via shfl, row clamped); lanes c>=38 keep zeros
__device__ __forceinline__ void ld4e(const __half* __restrict__ E, int tok, int len,
                                     int l0, int c, uint4* R) {
    #pragma unroll
    for (int i = 0; i < 4; ++i) {
        int lc = l0 + i; lc = (lc < len) ? lc : (len - 1);
        const int t = __shfl(tok, lc);
        if (c < 38) R[i] = *(const uint4*)(E + (size_t)t * HH + 8 * c);
    }
}
// 4 rows of a fp16 [rows][HH] matrix, row clamped to rmax
__device__ __forceinline__ void ld4h(const __half* __restrict__ M, int rmax,
                                     int r0, int c, uint4* R) {
    #pragma unroll
    for (int i = 0; i < 4; ++i) {
        int rc = r0 + i; rc = (rc < rmax) ? rc : rmax;
        if (c < 38) R[i] = *(const uint4*)(M + (size_t)rc * HH + 8 * c);
    }
}
__device__ __forceinline__ void store300(float* out, int c, const float z8[8]) {
    float4* o4 = (float4*)out;
    if (c < 37) {
        o4[2*c]   = make_float4(z8[0], z8[1], z8[2], z8[3]);
        o4[2*c+1] = make_float4(z8[4], z8[5], z8[6], z8[7]);
    } else if (c == 37) {
        o4[74]    = make_float4(z8[0], z8[1], z8[2], z8[3]);
    }
}

// ============ conversion kernels ============
__global__ __launch_bounds__(256) void k_cvt_emb(const float* __restrict__ emb,
                                                 __half* __restrict__ emb16) {
    const int id = blockIdx.x * 256 + threadIdx.x;     // one 4-col group
    if (id >= 50000 * 76) return;
    const int row = id / 76;
    const int c4  = (id - row * 76) * 4;
    float4 v = make_float4(0.f, 0.f, 0.f, 0.f);
    if (c4 < DD) v = *(const float4*)(emb + (size_t)row * DD + c4);
    const __half2 h0 = __floats2half2_rn(v.x, v.y);
    const __half2 h1 = __floats2half2_rn(v.z, v.w);
    uint2 pk;
    pk.x = *(const unsigned int*)&h0;
    pk.y = *(const unsigned int*)&h1;
    *(uint2*)(emb16 + (size_t)row * HH + c4) = pk;
}
__global__ __launch_bounds__(256) void k_cvt_small(const float* __restrict__ W_w,
                                                   const float* __restrict__ T_w,
                                                   __half* __restrict__ W16,
                                                   __half* __restrict__ T16) {
    int id = blockIdx.x * 256 + threadIdx.x;
    if (id < KK * HH) {
        const int k = id / HH, d = id - k * HH;
        W16[id] = __float2half((d < DD) ? W_w[(size_t)k * DD + d] : 0.f);
        return;
    }
    id -= KK * HH;
    if (id < 64 * HH) {
        const int k = id / HH, d = id - k * HH;
        T16[id] = __float2half((k < KK && d < DD) ? T_w[(size_t)d * KK + k] : 0.f);
    }
}

// ============ K1: y — wave-per-segment fp16 chunk-8 gather ============
__global__ __launch_bounds__(256, 4) void k_y16(
    const __half* __restrict__ emb16,
    const int* __restrict__ tokens,
    const int* __restrict__ seg_starts,
    const int* __restrict__ seg_lens,
    float* __restrict__ out_y)
{
    const int lane = threadIdx.x & 63;
    const int seg  = blockIdx.x * 4 + (threadIdx.x >> 6);
    const int len  = seg_lens[seg];
    const int base = (seg >> 7) * SS + seg_starts[seg];
    const int tok  = tokens[base + lane];
    const int c    = lane;

    uint4 A0[4] = {}, A1[4] = {};
    float a8[8] = {0.f,0.f,0.f,0.f,0.f,0.f,0.f,0.f};

    const int len8 = (len + 7) & ~7;
    ld4e(emb16, tok, len, 0, c, A0);
    for (int l0 = 0; l0 < len8; l0 += 8) {
        ld4e(emb16, tok, len, l0 + 4, c, A1);
        #pragma unroll
        for (int i = 0; i < 4; ++i) {
            const float m = (l0 + i < len) ? 1.f : 0.f;
            fma8(a8, m, A0[i]);
        }
        ld4e(emb16, tok, len, l0 + 8, c, A0);
        #pragma unroll
        for (int i = 0; i < 4; ++i) {
            const float m = (l0 + 4 + i < len) ? 1.f : 0.f;
            fma8(a8, m, A1[i]);
        }
    }
    const float inv = 1.f / (float)len;
    #pragma unroll
    for (int i = 0; i < 8; ++i) a8[i] *= inv;
    store300(out_y + (size_t)seg * DD, c, a8);
}

// ============ K2: u = y @ M_w (shared by both paths) ============
__global__ __launch_bounds__(NTU) void k_u(
    const float* __restrict__ y,
    const float* __restrict__ M_w,
    float* __restrict__ u)
{
    const int tid  = threadIdx.x;
    const int row0 = blockIdx.x * TMU;
    if (tid >= DD) return;

    float acc[TMU];
    #pragma unroll
    for (int r = 0; r < TMU; ++r) acc[r] = 0.f;

    #pragma unroll 5
    for (int e = 0; e < DD; ++e) {
        const float m = M_w[(size_t)e * DD + tid];
        #pragma unroll
        for (int r = 0; r < TMU; ++r)
            acc[r] += m * y[(size_t)(row0 + r) * DD + e];
    }
    #pragma unroll
    for (int r = 0; r < TMU; ++r)
        u[(size_t)(row0 + r) * DD + tid] = acc[r];
}

// ============ K3: esc/softmax/z/p/r — wave-per-segment, fp16, zero LDS/barriers ============
__global__ __launch_bounds__(256, 4) void k_rest16(
    const __half* __restrict__ emb16,
    const __half* __restrict__ W16,
    const __half* __restrict__ T16,
    const int* __restrict__ tokens,
    const int* __restrict__ seg_starts,
    const int* __restrict__ seg_lens,
    const float* __restrict__ u_ws,
    float* __restrict__ out_z,
    float* __restrict__ out_p,
    float* __restrict__ out_r)
{
    const int lane = threadIdx.x & 63;
    const int seg  = blockIdx.x * 4 + (threadIdx.x >> 6);
    const int len  = seg_lens[seg];
    const int base = (seg >> 7) * SS + seg_starts[seg];
    const int tok  = tokens[base + lane];
    const int c    = lane;

    // u in lane-matched layout: lane c holds u[8c..8c+7] (f32)
    float u8[8] = {0.f,0.f,0.f,0.f,0.f,0.f,0.f,0.f};
    {
        const float4* u4 = (const float4*)(u_ws + (size_t)seg * DD);
        if (c < 38) {
            const float4 a = u4[2*c];
            u8[0]=a.x; u8[1]=a.y; u8[2]=a.z; u8[3]=a.w;
            if (c < 37) { const float4 b = u4[2*c+1]; u8[4]=b.x; u8[5]=b.y; u8[6]=b.z; u8[7]=b.w; }
        }
    }

    uint4 A0[4] = {}, A1[4] = {};

    // ---- esc: chunk-8 pipelined gather, 4 reduce chains per half-chunk ----
    float esc = 0.f;
    const int len8 = (len + 7) & ~7;
    ld4e(emb16, tok, len, 0, c, A0);
    for (int l0 = 0; l0 < len8; l0 += 8) {
        ld4e(emb16, tok, len, l0 + 4, c, A1);
        {
            float d0 = dot8(A0[0], u8), d1 = dot8(A0[1], u8);
            float d2 = dot8(A0[2], u8), d3 = dot8(A0[3], u8);
            d0 = wave_sum(d0); d1 = wave_sum(d1); d2 = wave_sum(d2); d3 = wave_sum(d3);
            esc = (lane == l0+0) ? d0 : esc; esc = (lane == l0+1) ? d1 : esc;
            esc = (lane == l0+2) ? d2 : esc; esc = (lane == l0+3) ? d3 : esc;
        }
        ld4e(emb16, tok, len, l0 + 8, c, A0);
        {
            float d0 = dot8(A1[0], u8), d1 = dot8(A1[1], u8);
            float d2 = dot8(A1[2], u8), d3 = dot8(A1[3], u8);
            d0 = wave_sum(d0); d1 = wave_sum(d1); d2 = wave_sum(d2); d3 = wave_sum(d3);
            esc = (lane == l0+4) ? d0 : esc; esc = (lane == l0+5) ? d1 : esc;
            esc = (lane == l0+6) ? d2 : esc; esc = (lane == l0+7) ? d3 : esc;
        }
    }

    // ---- softmax over rows, in-wave (lane = row) ----
    const float v  = (lane < len) ? esc : -INFINITY;
    const float mx = wave_max(v);
    const float ex = (lane < len) ? __expf(v - mx) : 0.f;
    const float sm = wave_sum(ex);
    const float alpha = ex / sm;            // 0 for pad lanes

    // ---- z: re-read rows (L2-hot), alpha-weighted ----
    float z8[8] = {0.f,0.f,0.f,0.f,0.f,0.f,0.f,0.f};
    ld4e(emb16, tok, len, 0, c, A0);
    for (int l0 = 0; l0 < len8; l0 += 8) {
        ld4e(emb16, tok, len, l0 + 4, c, A1);
        #pragma unroll
        for (int i = 0; i < 4; ++i) { const float a = __shfl(alpha, l0 + i);     fma8(z8, a, A0[i]); }
        ld4e(emb16, tok, len, l0 + 8, c, A0);
        #pragma unroll
        for (int i = 0; i < 4; ++i) { const float a = __shfl(alpha, l0 + 4 + i); fma8(z8, a, A1[i]); }
    }
    store300(out_z + (size_t)seg * DD, c, z8);

    // ---- p: 50 wave-dots vs z (W16 L1-hot), chunk-8 ----
    float sc = 0.f;
    ld4h(W16, KK - 1, 0, c, A0);
    for (int k0 = 0; k0 < 56; k0 += 8) {
        ld4h(W16, KK - 1, k0 + 4, c, A1);
        {
            float t0 = dot8(A0[0], z8), t1 = dot8(A0[1], z8);
            float t2 = dot8(A0[2], z8), t3 = dot8(A0[3], z8);
            t0 = wave_sum(t0); t1 = wave_sum(t1); t2 = wave_sum(t2); t3 = wave_sum(t3);
            sc = (lane == k0+0) ? t0 : sc; sc = (lane == k0+1) ? t1 : sc;
            sc = (lane == k0+2) ? t2 : sc; sc = (lane == k0+3) ? t3 : sc;
        }
        ld4h(W16, KK - 1, k0 + 8, c, A0);
        {
            float t0 = dot8(A1[0], z8), t1 = dot8(A1[1], z8);
            float t2 = dot8(A1[2], z8), t3 = dot8(A1[3], z8);
            t0 = wave_sum(t0); t1 = wave_sum(t1); t2 = wave_sum(t2); t3 = wave_sum(t3);
            sc = (lane == k0+4) ? t0 : sc; sc = (lane == k0+5) ? t1 : sc;
            sc = (lane == k0+6) ? t2 : sc; sc = (lane == k0+7) ? t3 : sc;
        }
    }
    const float vk  = (lane < KK) ? sc : -INFINITY;
    const float mxk = wave_max(vk);
    const float ek  = (lane < KK) ? __expf(vk - mxk) : 0.f;
    const float smk = wave_sum(ek);
    const float p   = ek / smk;             // 0 for lanes >= 50
    if (lane < KK) out_p[(size_t)seg * KK + lane] = p;

    // ---- r = p @ T^T via transposed zero-padded T16 ----
    float r8[8] = {0.f,0.f,0.f,0.f,0.f,0.f,0.f,0.f};
    ld4h(T16, 63, 0, c, A0);
    for (int k0 = 0; k0 < 56; k0 += 8) {
        ld4h(T16, 63, k0 + 4, c, A1);
        #pragma unroll
        for (int i = 0; i < 4; ++i) { const float pk = __shfl(p, k0 + i);     fma8(r8, pk, A0[i]); }
        ld4h(T16, 63, k0 + 8, c, A0);
        #pragma unroll
        for (int i = 0; i < 4; ++i) { const float pk = __shfl(p, k0 + 4 + i); fma8(r8, pk, A1[i]); }
    }
    store300(out_r + (size_t)seg * DD, c, r8);
}

// ==================== fallback path (r5, proven @182us) ====================
__global__ __launch_bounds__(NT) void fb_y(
    const float* __restrict__ emb, const int* __restrict__ tokens,
    const int* __restrict__ seg_starts, const int* __restrict__ seg_lens,
    float* __restrict__ out_y)
{
    __shared__ int   tok_s[LL];
    __shared__ float part[NW][NT];
    const int tid = threadIdx.x, wave = tid >> 6, lane = tid & 63;
    const int seg = blockIdx.x, b = seg >> 7;
    const int start = seg_starts[seg], len = seg_lens[seg];
    if (tid < LL) tok_s[tid] = tokens[b * SS + start + tid];
    __syncthreads();
    float rr[NJ][NC];
    #pragma unroll
    for (int j = 0; j < NJ; ++j) {
        const int l = wave + j * NW;
        const int lc = (l < len) ? l : (len - 1);
        const float* row = emb + (size_t)tok_s[lc] * DD;
        rr[j][0] = row[lane]; rr[j][1] = row[lane+64]; rr[j][2] = row[lane+128];
        rr[j][3] = row[lane+192]; rr[j][4] = (lane < 44) ? row[lane+256] : 0.f;
    }
    float acc[NC] = {0.f,0.f,0.f,0.f,0.f};
    #pragma unroll
    for (int j = 0; j < NJ; ++j) {
        const int l = wave + j * NW;
        const float m = (l < len) ? 1.f : 0.f;
        #pragma unroll
        for (int cc = 0; cc < NC; ++cc) acc[cc] += m * rr[j][cc];
    }
    #pragma unroll
    for (int cc = 0; cc < NC; ++cc) part[wave][lane + 64*cc] = acc[cc];
    __syncthreads();
    if (tid < DD) {
        const float s = part[0][tid]+part[1][tid]+part[2][tid]+part[3][tid]+part[4][tid];
        out_y[(size_t)seg * DD + tid] = s / (float)len;
    }
}
__global__ __launch_bounds__(NT) void fb_rest(
    const float* __restrict__ emb, const float* __restrict__ W_w,
    const float* __restrict__ T_w, const int* __restrict__ tokens,
    const int* __restrict__ seg_starts, const int* __restrict__ seg_lens,
    const float* __restrict__ u_ws, float* __restrict__ out_z,
    float* __restrict__ out_p, float* __restrict__ out_r)
{
    __shared__ int   tok_s[LL];
    __shared__ float a_s[LL + 1];
    __shared__ float zp_s[NW][NT];
    __shared__ float z_s[NT];
    __shared__ float p_s[64];
    const int tid = threadIdx.x, wave = tid >> 6, lane = tid & 63;
    const int seg = blockIdx.x, b = seg >> 7;
    const int start = seg_starts[seg], len = seg_lens[seg];
    if (tid < LL) tok_s[tid] = tokens[b * SS + start + tid];
    __syncthreads();
    float uu[NC];
    {
        const float* up = u_ws + (size_t)seg * DD;
        uu[0]=up[lane]; uu[1]=up[lane+64]; uu[2]=up[lane+128]; uu[3]=up[lane+192];
        uu[4]=(lane < 44) ? up[lane+256] : 0.f;
    }
    float rr[NJ][NC];
    #pragma unroll
    for (int j = 0; j < NJ; ++j) {
        const int l = wave + j * NW;
        const int lc = (l < len) ? l : (len - 1);
        const float* row = emb + (size_t)tok_s[lc] * DD;
        rr[j][0]=row[lane]; rr[j][1]=row[lane+64]; rr[j][2]=row[lane+128];
        rr[j][3]=row[lane+192]; rr[j][4]=(lane<44)?row[lane+256]:0.f;
    }
    #pragma unroll
    for (int j = 0; j < NJ; ++j) {
        const int l = wave + j * NW;
        float dot = rr[j][0]*uu[0]+rr[j][1]*uu[1]+rr[j][2]*uu[2]+rr[j][3]*uu[3]+rr[j][4]*uu[4];
        dot = wave_sum(dot);
        if (lane == 0 && l < len) a_s[l] = dot;
    }
    __syncthreads();
    if (wave == 0) {
        const float vv = (lane < len) ? a_s[lane] : -INFINITY;
        const float mx = wave_max(vv);
        const float e  = (lane < len) ? __expf(vv - mx) : 0.f;
        const float sm = wave_sum(e);
        a_s[lane] = e / sm;
    }
    if (tid == NT - 1) a_s[LL] = 0.f;
    __syncthreads();
    {
        float zacc[NC] = {0.f,0.f,0.f,0.f,0.f};
        #pragma unroll
        for (int j = 0; j < NJ; ++j) {
            const int l = wave + j * NW;
            const float a = a_s[l];
            #pragma unroll
            for (int cc = 0; cc < NC; ++cc) zacc[cc] += a * rr[j][cc];
        }
        #pragma unroll
        for (int cc = 0; cc < NC; ++cc) zp_s[wave][lane + 64*cc] = zacc[cc];
    }
    __syncthreads();
    if (tid < DD) {
        const float zv = zp_s[0][tid]+zp_s[1][tid]+zp_s[2][tid]+zp_s[3][tid]+zp_s[4][tid];
        z_s[tid] = zv;
        out_z[(size_t)seg * DD + tid] = zv;
    }
    __syncthreads();
    for (int k = wave; k < KK; k += NW) {
        const float* wr = W_w + (size_t)k * DD;
        float d0 = wr[lane]*z_s[lane] + wr[lane+64]*z_s[lane+64]
                 + wr[lane+128]*z_s[lane+128] + wr[lane+192]*z_s[lane+192];
        if (lane < 44) d0 += wr[lane+256]*z_s[lane+256];
        d0 = wave_sum(d0);
        if (lane == 0) p_s[k] = d0;
    }
    __syncthreads();
    if (wave == 0) {
        const float vv = (lane < KK) ? p_s[lane] : -INFINITY;
        const float mx = wave_max(vv);
        const float e  = (lane < KK) ? __expf(vv - mx) : 0.f;
        const float sm = wave_sum(e);
        if (lane < KK) { const float p = e/sm; p_s[lane] = p; out_p[(size_t)seg*KK+lane] = p; }
    }
    __syncthreads();
    if (tid < DD) {
        const float* trow = T_w + (size_t)tid * KK;
        float acc = 0.f;
        #pragma unroll
        for (int k = 0; k < KK; ++k) acc += p_s[k] * trow[k];
        out_r[(size_t)seg * DD + tid] = acc;
    }
}

extern "C" void kernel_launch(void* const* d_in, const int* in_sizes, int n_in,
                              void* d_out, int out_size, void* d_ws, size_t ws_size,
                              hipStream_t stream) {
    const float* emb        = (const float*)d_in[0];
    const float* M_w        = (const float*)d_in[1];
    const float* W_w        = (const float*)d_in[2];
    const float* T_w        = (const float*)d_in[3];
    const int*   tokens     = (const int*)d_in[4];
    const int*   seg_starts = (const int*)d_in[5];
    const int*   seg_lens   = (const int*)d_in[6];

    float* out   = (float*)d_out;
    float* out_y = out;
    float* out_z = out + (size_t)NSEG * DD;
    float* out_p = out + (size_t)2 * NSEG * DD;
    float* out_r = out + (size_t)2 * NSEG * DD + (size_t)NSEG * KK;

    char* ws = (char*)d_ws;
    const size_t need = EMB16_BYTES + U_BYTES + W16_BYTES + T16_BYTES;

    if (ws_size >= need) {
        __half* emb16 = (__half*)ws;
        float*  u_ws  = (float*)(ws + EMB16_BYTES);
        __half* W16   = (__half*)(ws + EMB16_BYTES + U_BYTES);
        __half* T16   = (__half*)(ws + EMB16_BYTES + U_BYTES + W16_BYTES);

        hipLaunchKernelGGL(k_cvt_emb, dim3((50000*76 + 255)/256), dim3(256), 0, stream,
                           emb, emb16);
        hipLaunchKernelGGL(k_cvt_small, dim3(((KK+64)*HH + 255)/256), dim3(256), 0, stream,
                           W_w, T_w, W16, T16);
        hipLaunchKernelGGL(k_y16, dim3(NSEG/4), dim3(256), 0, stream,
                           emb16, tokens, seg_starts, seg_lens, out_y);
        hipLaunchKernelGGL(k_u, dim3(NSEG/TMU), dim3(NTU), 0, stream,
                           out_y, M_w, u_ws);
        hipLaunchKernelGGL(k_rest16, dim3(NSEG/4), dim3(256), 0, stream,
                           emb16, W16, T16, tokens, seg_starts, seg_lens,
                           u_ws, out_z, out_p, out_r);
    } else {
        float* u_ws = (float*)ws;   // 4.9 MB
        hipLaunchKernelGGL(fb_y, dim3(NSEG), dim3(NT), 0, stream,
                           emb, tokens, seg_starts, seg_lens, out_y);
        hipLaunchKernelGGL(k_u, dim3(NSEG/TMU), dim3(NTU), 0, stream,
                           out_y, M_w, u_ws);
        hipLaunchKernelGGL(fb_rest, dim3(NSEG), dim3(NT), 0, stream,
                           emb, W_w, T_w, tokens, seg_starts, seg_lens,
                           u_ws, out_z, out_p, out_r);
    }
}